// Round 1
// baseline (7009.437 us; speedup 1.0000x reference)
//
#include <hip/hip_runtime.h>
#include <math.h>

#define B_SZ 2
#define LSEQ 2048
#define DM   1024
#define DI   2048
#define DS   64
#define NTOK (B_SZ*LSEQ)
#define EPSV 1e-5f

static __device__ __forceinline__ float sigmoidf_(float v) {
    return 1.f / (1.f + __expf(-v));
}
static __device__ __forceinline__ float softplus_(float v) {
    // stable: max(v,0) + log1p(exp(-|v|))  (matches jax.nn.softplus)
    return fmaxf(v, 0.f) + log1pf(__expf(-fabsf(v)));
}

// ---------------- adaln modulation: mod[b][j] = bias[j] + sum_k c[b][k] * w[k][j]
__global__ void mod_kernel(const float* __restrict__ c, const float* __restrict__ w,
                           const float* __restrict__ bias, float* __restrict__ mod) {
    int idx = blockIdx.x * 256 + threadIdx.x;   // B*3072 = 6144 outputs
    int b = idx / 3072, j = idx % 3072;
    const float* cb = c + b * 1024;
    float acc = bias[j];
#pragma unroll 4
    for (int k = 0; k < 1024; ++k) acc = fmaf(cb[k], w[k * 3072 + j], acc);
    mod[idx] = acc;
}

// ---------------- layernorm + adaln scale/shift; one block per token row
__global__ __launch_bounds__(256) void adaln_kernel(const float* __restrict__ x,
                                                    const float* __restrict__ mod,
                                                    float* __restrict__ h) {
    int row = blockIdx.x;
    int b = row >> 11;                     // row / LSEQ
    const float* xr = x + (size_t)row * DM;
    float v[4], s = 0.f, s2 = 0.f;
#pragma unroll
    for (int i = 0; i < 4; ++i) {
        v[i] = xr[threadIdx.x + i * 256];
        s += v[i]; s2 += v[i] * v[i];
    }
#pragma unroll
    for (int off = 32; off; off >>= 1) { s += __shfl_xor(s, off); s2 += __shfl_xor(s2, off); }
    __shared__ float red[8];
    int wid = threadIdx.x >> 6;
    if ((threadIdx.x & 63) == 0) { red[wid] = s; red[4 + wid] = s2; }
    __syncthreads();
    s  = red[0] + red[1] + red[2] + red[3];
    s2 = red[4] + red[5] + red[6] + red[7];
    float mu  = s * (1.f / DM);
    float var = s2 * (1.f / DM) - mu * mu;
    float rstd = rsqrtf(var + EPSV);
    const float* mb = mod + b * 3072;
    float* hr = h + (size_t)row * DM;
#pragma unroll
    for (int i = 0; i < 4; ++i) {
        int d = threadIdx.x + i * 256;
        hr[d] = (v[i] - mu) * rstd * (1.f + mb[1024 + d]) + mb[d];
    }
}

// ---------------- fp32 GEMM: C(M,N) = A(M,K; lda) @ W(K,N; ldb), 64x64 tile, 4x4/thread
__global__ __launch_bounds__(256) void gemm_kernel(
    const float* __restrict__ A, int lda,
    const float* __restrict__ Bw, int ldb,
    float* __restrict__ C, int ldc,
    int K, int accum)
{
    __shared__ float As[16][68];   // K-major, padded (16B-aligned rows: 68*4=272)
    __shared__ float Bs[16][68];
    int tid = threadIdx.x;
    int bm = blockIdx.y * 64;
    int bn = blockIdx.x * 64;
    int tx = tid & 15, ty = tid >> 4;
    int arow = tid >> 2, acol = (tid & 3) << 2;   // A stage: 64 rows x 16 k (float4 over k)
    int brow = tid >> 4, bcol = (tid & 15) << 2;  // B stage: 16 k x 64 n (float4 over n)
    const float* aptr = A + (size_t)(bm + arow) * lda + acol;
    const float* bptr = Bw + (size_t)brow * ldb + bn + bcol;
    float acc[4][4] = {};
    for (int k0 = 0; k0 < K; k0 += 16) {
        float4 av = *(const float4*)(aptr + k0);
        float4 bv = *(const float4*)(bptr + (size_t)k0 * ldb);
        __syncthreads();
        As[acol + 0][arow] = av.x;
        As[acol + 1][arow] = av.y;
        As[acol + 2][arow] = av.z;
        As[acol + 3][arow] = av.w;
        *(float4*)&Bs[brow][bcol] = bv;
        __syncthreads();
#pragma unroll
        for (int k = 0; k < 16; ++k) {
            float4 a4 = *(const float4*)&As[k][ty << 2];
            float4 b4 = *(const float4*)&Bs[k][tx << 2];
            float ar[4] = {a4.x, a4.y, a4.z, a4.w};
            float br[4] = {b4.x, b4.y, b4.z, b4.w};
#pragma unroll
            for (int i = 0; i < 4; ++i)
#pragma unroll
                for (int j = 0; j < 4; ++j)
                    acc[i][j] = fmaf(ar[i], br[j], acc[i][j]);
        }
    }
#pragma unroll
    for (int i = 0; i < 4; ++i) {
        float* cp = C + (size_t)(bm + (ty << 2) + i) * ldc + bn + (tx << 2);
        float4 val = {acc[i][0], acc[i][1], acc[i][2], acc[i][3]};
        if (accum) {
            float4 old = *(const float4*)cp;
            val.x += old.x; val.y += old.y; val.z += old.z; val.w += old.w;
        }
        *(float4*)cp = val;
    }
}

// ---------------- silu in place on xs half of xz (cols 0..2047 of 4096-wide rows)
__global__ void silu_xs_kernel(float* __restrict__ xz) {
    int idx = blockIdx.x * 256 + threadIdx.x;   // NTOK*512 float4 groups
    int row = idx >> 9, c = (idx & 511) << 2;
    float4* p = (float4*)(xz + (size_t)row * 4096 + c);
    float4 v = *p;
    v.x *= sigmoidf_(v.x); v.y *= sigmoidf_(v.y);
    v.z *= sigmoidf_(v.z); v.w *= sigmoidf_(v.w);
    *p = v;
}

// ---------------- dt = softplus(proj[:, :2048] + dt_bias), in place
__global__ void dtprep_kernel(float* __restrict__ proj, const float* __restrict__ dtb) {
    int idx = blockIdx.x * 256 + threadIdx.x;   // NTOK*512 float4 groups
    int row = idx >> 9, c = (idx & 511) << 2;
    float4* p = (float4*)(proj + (size_t)row * 2176 + c);
    float4 bv = *(const float4*)(dtb + c);
    float4 v = *p;
    v.x = softplus_(v.x + bv.x); v.y = softplus_(v.y + bv.y);
    v.z = softplus_(v.z + bv.z); v.w = softplus_(v.w + bv.w);
    *p = v;
}

// ---------------- selective scan: one wave per (b,d) channel, lane = state s
// y[t,d] = (sum_s h_s * C_s + xs*D) * silu(z);  bwd direction runs t descending
__global__ __launch_bounds__(256) void scan_kernel(
    const float* __restrict__ proj, const float* __restrict__ xz,
    const float* __restrict__ A_log, const float* __restrict__ Dsk,
    float* __restrict__ y, int reverse)
{
    int gtid = blockIdx.x * 256 + threadIdx.x;
    int wave = gtid >> 6, lane = gtid & 63;
    int b = wave >> 11, d = wave & 2047;
    float A  = -__expf(A_log[d * 64 + lane]);
    float Dv = Dsk[d];
    const float* projb = proj + (size_t)b * LSEQ * 2176;
    const float* xzb   = xz   + (size_t)b * LSEQ * 4096;
    float* yb          = y    + (size_t)b * LSEQ * 2048;
    float h = 0.f;
    for (int i = 0; i < LSEQ; ++i) {
        int t = reverse ? (LSEQ - 1 - i) : i;
        const float* prow = projb + (size_t)t * 2176;
        float dt = prow[d];
        float Bt = prow[2048 + lane];
        float Ct = prow[2112 + lane];
        float xt = xzb[(size_t)t * 4096 + d];
        h = fmaf(h, __expf(dt * A), dt * xt * Bt);
        float p = h * Ct;
#pragma unroll
        for (int off = 32; off; off >>= 1) p += __shfl_xor(p, off);
        if (lane == 0) {
            float zt = xzb[(size_t)t * 4096 + 2048 + d];
            yb[(size_t)t * 2048 + d] = (p + xt * Dv) * (zt * sigmoidf_(zt));
        }
    }
}

// ---------------- out = x + gate * v   (gate = mod[b][2048+d]); safe in-place (out==x)
__global__ void gated_add_kernel(const float* __restrict__ x, const float* __restrict__ v,
                                 const float* __restrict__ mod, float* __restrict__ out) {
    int idx = blockIdx.x * 256 + threadIdx.x;   // NTOK*256 float4 groups
    int row = idx >> 8, b = row >> 11, c = (idx & 255) << 2;
    size_t o = (size_t)row * 1024 + c;
    float4 xv = *(const float4*)(x + o);
    float4 hv = *(const float4*)(v + o);
    float4 gv = *(const float4*)(mod + b * 3072 + 2048 + c);
    float4 r = {fmaf(gv.x, hv.x, xv.x), fmaf(gv.y, hv.y, xv.y),
                fmaf(gv.z, hv.z, xv.z), fmaf(gv.w, hv.w, xv.w)};
    *(float4*)(out + o) = r;
}

// ---------------- g = silu(a) * b
__global__ void silumul_kernel(const float* __restrict__ a, const float* __restrict__ bb,
                               float* __restrict__ g) {
    int idx = blockIdx.x * 256 + threadIdx.x;   // NTOK*512 float4 groups
    size_t o = (size_t)idx << 2;
    float4 av = *(const float4*)(a + o);
    float4 bv = *(const float4*)(bb + o);
    float4 r = {av.x * sigmoidf_(av.x) * bv.x, av.y * sigmoidf_(av.y) * bv.y,
                av.z * sigmoidf_(av.z) * bv.z, av.w * sigmoidf_(av.w) * bv.w};
    *(float4*)(g + o) = r;
}

extern "C" void kernel_launch(void* const* d_in, const int* in_sizes, int n_in,
                              void* d_out, int out_size, void* d_ws, size_t ws_size,
                              hipStream_t stream) {
    const float* x         = (const float*)d_in[0];
    const float* c         = (const float*)d_in[1];
    const float* adw_mamba = (const float*)d_in[2];
    const float* adb_mamba = (const float*)d_in[3];
    const float* adw_mlp   = (const float*)d_in[4];
    const float* adb_mlp   = (const float*)d_in[5];
    const float* mlp_w1    = (const float*)d_in[6];
    const float* mlp_w2    = (const float*)d_in[7];
    const float* mlp_w3    = (const float*)d_in[8];
    const float* in_w[2]    = {(const float*)d_in[9],  (const float*)d_in[15]};
    const float* xproj_w[2] = {(const float*)d_in[10], (const float*)d_in[16]};
    const float* dt_bias[2] = {(const float*)d_in[11], (const float*)d_in[17]};
    const float* A_log[2]   = {(const float*)d_in[12], (const float*)d_in[18]};
    const float* Dsk[2]     = {(const float*)d_in[13], (const float*)d_in[19]};
    const float* out_w[2]   = {(const float*)d_in[14], (const float*)d_in[20]};
    float* out = (float*)d_out;

    // workspace layout (floats)
    float* ws   = (float*)d_ws;
    float* mod  = ws;                             // 2 * B * 3072 = 12288
    float* h    = mod  + 12288;                   // NTOK*1024   (h, then h2)
    float* xz   = h    + (size_t)NTOK * 1024;     // NTOK*4096   (xz; then mlp a|b)
    float* proj = xz   + (size_t)NTOK * 4096;     // NTOK*2176
    float* yb   = proj + (size_t)NTOK * 2176;     // NTOK*2048   (y; then g)
    float* hsum = yb   + (size_t)NTOK * 2048;     // NTOK*1024   (fwd+bwd; then mlp_out)

    dim3 blk(256);

    mod_kernel<<<24, blk, 0, stream>>>(c, adw_mamba, adb_mamba, mod);
    mod_kernel<<<24, blk, 0, stream>>>(c, adw_mlp,   adb_mlp,   mod + 6144);
    adaln_kernel<<<NTOK, blk, 0, stream>>>(x, mod, h);

    for (int dir = 0; dir < 2; ++dir) {
        // xz = h @ in_w         (4096x1024 @ 1024x4096)
        gemm_kernel<<<dim3(64, 64), blk, 0, stream>>>(h, 1024, in_w[dir], 4096, xz, 4096, 1024, 0);
        silu_xs_kernel<<<8192, blk, 0, stream>>>(xz);
        // proj = xs @ xproj_w   (4096x2048 @ 2048x2176), xs = first half of xz (lda 4096)
        gemm_kernel<<<dim3(34, 64), blk, 0, stream>>>(xz, 4096, xproj_w[dir], 2176, proj, 2176, 2048, 0);
        dtprep_kernel<<<8192, blk, 0, stream>>>(proj, dt_bias[dir]);
        // selective scan (bwd = reverse time; flips cancel since all other ops are per-t)
        scan_kernel<<<1024, blk, 0, stream>>>(proj, xz, A_log[dir], Dsk[dir], yb, dir);
        // hsum (+)= y @ out_w   (4096x2048 @ 2048x1024); dir0 store, dir1 accumulate
        gemm_kernel<<<dim3(16, 64), blk, 0, stream>>>(yb, 2048, out_w[dir], 1024, hsum, 1024, 2048, dir);
    }

    // x_new = x + gate_mamba * hsum   -> stored in d_out
    gated_add_kernel<<<4096, blk, 0, stream>>>(x, hsum, mod, out);
    // second adaln
    adaln_kernel<<<NTOK, blk, 0, stream>>>(out, mod + 6144, h);
    // mlp: a = h@w1, b = h@w2 (reuse xz), g = silu(a)*b (reuse yb), mlp_out = g@w3 (reuse hsum)
    gemm_kernel<<<dim3(32, 64), blk, 0, stream>>>(h, 1024, mlp_w1, 2048, xz, 2048, 1024, 0);
    gemm_kernel<<<dim3(32, 64), blk, 0, stream>>>(h, 1024, mlp_w2, 2048, xz + (size_t)NTOK * 2048, 2048, 1024, 0);
    silumul_kernel<<<8192, blk, 0, stream>>>(xz, xz + (size_t)NTOK * 2048, yb);
    gemm_kernel<<<dim3(16, 64), blk, 0, stream>>>(yb, 2048, mlp_w3, 1024, hsum, 1024, 2048, 0);
    // final: out = x_new + gate_mlp * mlp_out  (in-place on d_out)
    gated_add_kernel<<<4096, blk, 0, stream>>>(out, hsum, mod + 6144, out);
}

// Round 2
// 4997.571 us; speedup vs baseline: 1.4026x; 1.4026x over previous
//
#include <hip/hip_runtime.h>
#include <math.h>

#define B_SZ 2
#define LSEQ 2048
#define DM   1024
#define DI   2048
#define DS   64
#define NTOK (B_SZ*LSEQ)
#define EPSV 1e-5f

static __device__ __forceinline__ float sigmoidf_(float v) {
    return 1.f / (1.f + __expf(-v));
}
static __device__ __forceinline__ float softplus_(float v) {
    // stable: max(v,0) + log1p(exp(-|v|))  (matches jax.nn.softplus)
    return fmaxf(v, 0.f) + log1pf(__expf(-fabsf(v)));
}

// ---------------- adaln modulation: mod[b][j] = bias[j] + sum_k c[b][k] * w[k][j]
// 96 blocks; each block: 32 j's x both batch rows; 256 thr = 32 j x 8 k-slices of 128.
// w row read once, used for both b (halves streamed bytes vs per-b).
__global__ __launch_bounds__(256) void mod_kernel(const float* __restrict__ c,
                                                  const float* __restrict__ w,
                                                  const float* __restrict__ bias,
                                                  float* __restrict__ mod) {
    int jt = blockIdx.x * 32;
    int jj = threadIdx.x & 31, ks = threadIdx.x >> 5;
    int j = jt + jj;
    const float* c0 = c;
    const float* c1 = c + 1024;
    float a0 = 0.f, a1 = 0.f;
    int k0 = ks * 128;
#pragma unroll 4
    for (int k = k0; k < k0 + 128; ++k) {
        float wv = w[(size_t)k * 3072 + j];
        a0 = fmaf(c0[k], wv, a0);
        a1 = fmaf(c1[k], wv, a1);
    }
    __shared__ float red[2][8][32];
    red[0][ks][jj] = a0;
    red[1][ks][jj] = a1;
    __syncthreads();
    if (threadIdx.x < 64) {
        int bb = threadIdx.x >> 5, j2 = threadIdx.x & 31;
        float s = bias[jt + j2];
#pragma unroll
        for (int kk = 0; kk < 8; ++kk) s += red[bb][kk][j2];
        mod[bb * 3072 + jt + j2] = s;
    }
}

// ---------------- layernorm + adaln scale/shift; one block per token row
__global__ __launch_bounds__(256) void adaln_kernel(const float* __restrict__ x,
                                                    const float* __restrict__ mod,
                                                    float* __restrict__ h) {
    int row = blockIdx.x;
    int b = row >> 11;                     // row / LSEQ
    const float* xr = x + (size_t)row * DM;
    float v[4], s = 0.f, s2 = 0.f;
#pragma unroll
    for (int i = 0; i < 4; ++i) {
        v[i] = xr[threadIdx.x + i * 256];
        s += v[i]; s2 += v[i] * v[i];
    }
#pragma unroll
    for (int off = 32; off; off >>= 1) { s += __shfl_xor(s, off); s2 += __shfl_xor(s2, off); }
    __shared__ float red[8];
    int wid = threadIdx.x >> 6;
    if ((threadIdx.x & 63) == 0) { red[wid] = s; red[4 + wid] = s2; }
    __syncthreads();
    s  = red[0] + red[1] + red[2] + red[3];
    s2 = red[4] + red[5] + red[6] + red[7];
    float mu  = s * (1.f / DM);
    float var = s2 * (1.f / DM) - mu * mu;
    float rstd = rsqrtf(var + EPSV);
    const float* mb = mod + b * 3072;
    float* hr = h + (size_t)row * DM;
#pragma unroll
    for (int i = 0; i < 4; ++i) {
        int d = threadIdx.x + i * 256;
        hr[d] = (v[i] - mu) * rstd * (1.f + mb[1024 + d]) + mb[d];
    }
}

// ---------------- fp32 GEMM: C(M,N) = A(M,K; lda) @ W(K,N; ldb), 64x64 tile, 4x4/thread
__global__ __launch_bounds__(256) void gemm_kernel(
    const float* __restrict__ A, int lda,
    const float* __restrict__ Bw, int ldb,
    float* __restrict__ C, int ldc,
    int K, int accum)
{
    __shared__ float As[16][68];   // K-major, padded
    __shared__ float Bs[16][68];
    int tid = threadIdx.x;
    int bm = blockIdx.y * 64;
    int bn = blockIdx.x * 64;
    int tx = tid & 15, ty = tid >> 4;
    int arow = tid >> 2, acol = (tid & 3) << 2;
    int brow = tid >> 4, bcol = (tid & 15) << 2;
    const float* aptr = A + (size_t)(bm + arow) * lda + acol;
    const float* bptr = Bw + (size_t)brow * ldb + bn + bcol;
    float acc[4][4] = {};
    for (int k0 = 0; k0 < K; k0 += 16) {
        float4 av = *(const float4*)(aptr + k0);
        float4 bv = *(const float4*)(bptr + (size_t)k0 * ldb);
        __syncthreads();
        As[acol + 0][arow] = av.x;
        As[acol + 1][arow] = av.y;
        As[acol + 2][arow] = av.z;
        As[acol + 3][arow] = av.w;
        *(float4*)&Bs[brow][bcol] = bv;
        __syncthreads();
#pragma unroll
        for (int k = 0; k < 16; ++k) {
            float4 a4 = *(const float4*)&As[k][ty << 2];
            float4 b4 = *(const float4*)&Bs[k][tx << 2];
            float ar[4] = {a4.x, a4.y, a4.z, a4.w};
            float br[4] = {b4.x, b4.y, b4.z, b4.w};
#pragma unroll
            for (int i = 0; i < 4; ++i)
#pragma unroll
                for (int j = 0; j < 4; ++j)
                    acc[i][j] = fmaf(ar[i], br[j], acc[i][j]);
        }
    }
#pragma unroll
    for (int i = 0; i < 4; ++i) {
        float* cp = C + (size_t)(bm + (ty << 2) + i) * ldc + bn + (tx << 2);
        float4 val = {acc[i][0], acc[i][1], acc[i][2], acc[i][3]};
        if (accum) {
            float4 old = *(const float4*)cp;
            val.x += old.x; val.y += old.y; val.z += old.z; val.w += old.w;
        }
        *(float4*)cp = val;
    }
}

// ---------------- silu in place on xs half of xz (cols 0..2047 of 4096-wide rows)
__global__ void silu_xs_kernel(float* __restrict__ xz) {
    int idx = blockIdx.x * 256 + threadIdx.x;
    int row = idx >> 9, c = (idx & 511) << 2;
    float4* p = (float4*)(xz + (size_t)row * 4096 + c);
    float4 v = *p;
    v.x *= sigmoidf_(v.x); v.y *= sigmoidf_(v.y);
    v.z *= sigmoidf_(v.z); v.w *= sigmoidf_(v.w);
    *p = v;
}

// ---------------- dt = softplus(proj[:, :2048] + dt_bias), in place
__global__ void dtprep_kernel(float* __restrict__ proj, const float* __restrict__ dtb) {
    int idx = blockIdx.x * 256 + threadIdx.x;
    int row = idx >> 9, c = (idx & 511) << 2;
    float4* p = (float4*)(proj + (size_t)row * 2176 + c);
    float4 bv = *(const float4*)(dtb + c);
    float4 v = *p;
    v.x = softplus_(v.x + bv.x); v.y = softplus_(v.y + bv.y);
    v.z = softplus_(v.z + bv.z); v.w = softplus_(v.w + bv.w);
    *p = v;
}

// ---------------- selective scan: one wave per (b,d) channel, lane = state s
// T=8 time-unroll, double-buffered prefetch: loads for block k+1 issue before
// compute of block k -> converts latency-bound (R1: VALUBusy 35%) to
// throughput-bound. 8 independent exp/butterfly chains give in-wave ILP.
#define SCAN_T 8

#define SCAN_LOAD(dt_, Bt_, Ct_, xt_, zt_, t0_)                          \
    _Pragma("unroll")                                                    \
    for (int i_ = 0; i_ < SCAN_T; ++i_) {                                \
        int t_ = REV ? (LSEQ - 1 - ((t0_) + i_)) : ((t0_) + i_);         \
        const float* prow_ = projb + (size_t)t_ * 2176;                  \
        const float* xrow_ = xzb + (size_t)t_ * 4096;                    \
        dt_[i_] = prow_[d];                                              \
        Bt_[i_] = prow_[2048 + lane];                                    \
        Ct_[i_] = prow_[2112 + lane];                                    \
        xt_[i_] = xrow_[d];                                              \
        zt_[i_] = xrow_[2048 + d];                                       \
    }

#define SCAN_COMPUTE(dt_, Bt_, Ct_, xt_, zt_, t0_) {                     \
    float e_[SCAN_T], w_[SCAN_T], p_[SCAN_T], g_[SCAN_T];                \
    _Pragma("unroll")                                                    \
    for (int i_ = 0; i_ < SCAN_T; ++i_) {                                \
        e_[i_] = __expf(dt_[i_] * A);                                    \
        w_[i_] = dt_[i_] * xt_[i_] * Bt_[i_];                            \
        g_[i_] = zt_[i_] * sigmoidf_(zt_[i_]);                           \
    }                                                                    \
    _Pragma("unroll")                                                    \
    for (int i_ = 0; i_ < SCAN_T; ++i_) {                                \
        h = fmaf(h, e_[i_], w_[i_]);                                     \
        p_[i_] = h * Ct_[i_];                                            \
    }                                                                    \
    _Pragma("unroll")                                                    \
    for (int off_ = 32; off_; off_ >>= 1) {                              \
        _Pragma("unroll")                                                \
        for (int i_ = 0; i_ < SCAN_T; ++i_)                              \
            p_[i_] += __shfl_xor(p_[i_], off_);                          \
    }                                                                    \
    _Pragma("unroll")                                                    \
    for (int i_ = 0; i_ < SCAN_T; ++i_) {                                \
        float val_ = fmaf(xt_[i_], Dv, p_[i_]) * g_[i_];                 \
        int t_ = REV ? (LSEQ - 1 - ((t0_) + i_)) : ((t0_) + i_);         \
        if (lane == i_) yb[(size_t)t_ * 2048 + d] = val_;                \
    }                                                                    \
}

template <int REV>
__global__ __launch_bounds__(256) void scan_kernel(
    const float* __restrict__ proj, const float* __restrict__ xz,
    const float* __restrict__ A_log, const float* __restrict__ Dsk,
    float* __restrict__ y)
{
    int gtid = blockIdx.x * 256 + threadIdx.x;
    int wave = gtid >> 6, lane = gtid & 63;
    int b = wave >> 11, d = wave & 2047;
    float A  = -__expf(A_log[d * 64 + lane]);
    float Dv = Dsk[d];
    const float* projb = proj + (size_t)b * LSEQ * 2176;
    const float* xzb   = xz   + (size_t)b * LSEQ * 4096;
    float* yb          = y    + (size_t)b * LSEQ * 2048;
    float h = 0.f;

    float dA[SCAN_T], BA[SCAN_T], CA[SCAN_T], xA[SCAN_T], zA[SCAN_T];
    float dB[SCAN_T], BB[SCAN_T], CB[SCAN_T], xB[SCAN_T], zB[SCAN_T];

    SCAN_LOAD(dA, BA, CA, xA, zA, 0);
    for (int t0 = 0; t0 < LSEQ; t0 += 2 * SCAN_T) {
        SCAN_LOAD(dB, BB, CB, xB, zB, t0 + SCAN_T);
        SCAN_COMPUTE(dA, BA, CA, xA, zA, t0);
        if (t0 + 2 * SCAN_T < LSEQ) {
            SCAN_LOAD(dA, BA, CA, xA, zA, t0 + 2 * SCAN_T);
        }
        SCAN_COMPUTE(dB, BB, CB, xB, zB, t0 + SCAN_T);
    }
}

// ---------------- out = x + gate * v   (gate = mod[b][2048+d]); safe in-place (out==x)
__global__ void gated_add_kernel(const float* __restrict__ x, const float* __restrict__ v,
                                 const float* __restrict__ mod, float* __restrict__ out) {
    int idx = blockIdx.x * 256 + threadIdx.x;
    int row = idx >> 8, b = row >> 11, c = (idx & 255) << 2;
    size_t o = (size_t)row * 1024 + c;
    float4 xv = *(const float4*)(x + o);
    float4 hv = *(const float4*)(v + o);
    float4 gv = *(const float4*)(mod + b * 3072 + 2048 + c);
    float4 r = {fmaf(gv.x, hv.x, xv.x), fmaf(gv.y, hv.y, xv.y),
                fmaf(gv.z, hv.z, xv.z), fmaf(gv.w, hv.w, xv.w)};
    *(float4*)(out + o) = r;
}

// ---------------- g = silu(a) * b
__global__ void silumul_kernel(const float* __restrict__ a, const float* __restrict__ bb,
                               float* __restrict__ g) {
    int idx = blockIdx.x * 256 + threadIdx.x;
    size_t o = (size_t)idx << 2;
    float4 av = *(const float4*)(a + o);
    float4 bv = *(const float4*)(bb + o);
    float4 r = {av.x * sigmoidf_(av.x) * bv.x, av.y * sigmoidf_(av.y) * bv.y,
                av.z * sigmoidf_(av.z) * bv.z, av.w * sigmoidf_(av.w) * bv.w};
    *(float4*)(g + o) = r;
}

extern "C" void kernel_launch(void* const* d_in, const int* in_sizes, int n_in,
                              void* d_out, int out_size, void* d_ws, size_t ws_size,
                              hipStream_t stream) {
    const float* x         = (const float*)d_in[0];
    const float* c         = (const float*)d_in[1];
    const float* adw_mamba = (const float*)d_in[2];
    const float* adb_mamba = (const float*)d_in[3];
    const float* adw_mlp   = (const float*)d_in[4];
    const float* adb_mlp   = (const float*)d_in[5];
    const float* mlp_w1    = (const float*)d_in[6];
    const float* mlp_w2    = (const float*)d_in[7];
    const float* mlp_w3    = (const float*)d_in[8];
    const float* in_w[2]    = {(const float*)d_in[9],  (const float*)d_in[15]};
    const float* xproj_w[2] = {(const float*)d_in[10], (const float*)d_in[16]};
    const float* dt_bias[2] = {(const float*)d_in[11], (const float*)d_in[17]};
    const float* A_log[2]   = {(const float*)d_in[12], (const float*)d_in[18]};
    const float* Dsk[2]     = {(const float*)d_in[13], (const float*)d_in[19]};
    const float* out_w[2]   = {(const float*)d_in[14], (const float*)d_in[20]};
    float* out = (float*)d_out;

    // workspace layout (floats)
    float* ws   = (float*)d_ws;
    float* mod  = ws;                             // 2 * B * 3072 = 12288
    float* h    = mod  + 12288;                   // NTOK*1024   (h, then h2)
    float* xz   = h    + (size_t)NTOK * 1024;     // NTOK*4096   (xz; then mlp a|b)
    float* proj = xz   + (size_t)NTOK * 4096;     // NTOK*2176
    float* yb   = proj + (size_t)NTOK * 2176;     // NTOK*2048   (y; then g)
    float* hsum = yb   + (size_t)NTOK * 2048;     // NTOK*1024   (fwd+bwd; then mlp_out)

    dim3 blk(256);

    mod_kernel<<<96, blk, 0, stream>>>(c, adw_mamba, adb_mamba, mod);
    mod_kernel<<<96, blk, 0, stream>>>(c, adw_mlp,   adb_mlp,   mod + 6144);
    adaln_kernel<<<NTOK, blk, 0, stream>>>(x, mod, h);

    for (int dir = 0; dir < 2; ++dir) {
        // xz = h @ in_w         (4096x1024 @ 1024x4096)
        gemm_kernel<<<dim3(64, 64), blk, 0, stream>>>(h, 1024, in_w[dir], 4096, xz, 4096, 1024, 0);
        silu_xs_kernel<<<8192, blk, 0, stream>>>(xz);
        // proj = xs @ xproj_w   (4096x2048 @ 2048x2176)
        gemm_kernel<<<dim3(34, 64), blk, 0, stream>>>(xz, 4096, xproj_w[dir], 2176, proj, 2176, 2048, 0);
        dtprep_kernel<<<8192, blk, 0, stream>>>(proj, dt_bias[dir]);
        // selective scan (bwd = reverse time; flips cancel since all other ops are per-t)
        if (dir == 0)
            scan_kernel<0><<<1024, blk, 0, stream>>>(proj, xz, A_log[dir], Dsk[dir], yb);
        else
            scan_kernel<1><<<1024, blk, 0, stream>>>(proj, xz, A_log[dir], Dsk[dir], yb);
        // hsum (+)= y @ out_w   (4096x2048 @ 2048x1024); dir0 store, dir1 accumulate
        gemm_kernel<<<dim3(16, 64), blk, 0, stream>>>(yb, 2048, out_w[dir], 1024, hsum, 1024, 2048, dir);
    }

    // x_new = x + gate_mamba * hsum   -> stored in d_out
    gated_add_kernel<<<4096, blk, 0, stream>>>(x, hsum, mod, out);
    // second adaln
    adaln_kernel<<<NTOK, blk, 0, stream>>>(out, mod + 6144, h);
    // mlp: a = h@w1, b = h@w2 (reuse xz), g = silu(a)*b (reuse yb), mlp_out = g@w3 (reuse hsum)
    gemm_kernel<<<dim3(32, 64), blk, 0, stream>>>(h, 1024, mlp_w1, 2048, xz, 2048, 1024, 0);
    gemm_kernel<<<dim3(32, 64), blk, 0, stream>>>(h, 1024, mlp_w2, 2048, xz + (size_t)NTOK * 2048, 2048, 1024, 0);
    silumul_kernel<<<8192, blk, 0, stream>>>(xz, xz + (size_t)NTOK * 2048, yb);
    gemm_kernel<<<dim3(16, 64), blk, 0, stream>>>(yb, 2048, mlp_w3, 1024, hsum, 1024, 2048, 0);
    // final: out = x_new + gate_mlp * mlp_out  (in-place on d_out)
    gated_add_kernel<<<4096, blk, 0, stream>>>(out, hsum, mod + 6144, out);
}

// Round 3
// 4641.908 us; speedup vs baseline: 1.5100x; 1.0766x over previous
//
#include <hip/hip_runtime.h>
#include <math.h>

#define B_SZ 2
#define LSEQ 2048
#define DM   1024
#define DI   2048
#define DS   64
#define NTOK (B_SZ*LSEQ)
#define EPSV 1e-5f

static __device__ __forceinline__ float sigmoidf_(float v) {
    return 1.f / (1.f + __expf(-v));
}
static __device__ __forceinline__ float softplus_(float v) {
    // stable: max(v,0) + log1p(exp(-|v|))  (matches jax.nn.softplus)
    return fmaxf(v, 0.f) + log1pf(__expf(-fabsf(v)));
}

// ---------------- adaln modulation: mod[b][j] = bias[j] + sum_k c[b][k] * w[k][j]
__global__ __launch_bounds__(256) void mod_kernel(const float* __restrict__ c,
                                                  const float* __restrict__ w,
                                                  const float* __restrict__ bias,
                                                  float* __restrict__ mod) {
    int jt = blockIdx.x * 32;
    int jj = threadIdx.x & 31, ks = threadIdx.x >> 5;
    int j = jt + jj;
    const float* c0 = c;
    const float* c1 = c + 1024;
    float a0 = 0.f, a1 = 0.f;
    int k0 = ks * 128;
#pragma unroll 4
    for (int k = k0; k < k0 + 128; ++k) {
        float wv = w[(size_t)k * 3072 + j];
        a0 = fmaf(c0[k], wv, a0);
        a1 = fmaf(c1[k], wv, a1);
    }
    __shared__ float red[2][8][32];
    red[0][ks][jj] = a0;
    red[1][ks][jj] = a1;
    __syncthreads();
    if (threadIdx.x < 64) {
        int bb = threadIdx.x >> 5, j2 = threadIdx.x & 31;
        float s = bias[jt + j2];
#pragma unroll
        for (int kk = 0; kk < 8; ++kk) s += red[bb][kk][j2];
        mod[bb * 3072 + jt + j2] = s;
    }
}

// ---------------- layernorm + adaln scale/shift; one block per token row
__global__ __launch_bounds__(256) void adaln_kernel(const float* __restrict__ x,
                                                    const float* __restrict__ mod,
                                                    float* __restrict__ h) {
    int row = blockIdx.x;
    int b = row >> 11;
    const float* xr = x + (size_t)row * DM;
    float v[4], s = 0.f, s2 = 0.f;
#pragma unroll
    for (int i = 0; i < 4; ++i) {
        v[i] = xr[threadIdx.x + i * 256];
        s += v[i]; s2 += v[i] * v[i];
    }
#pragma unroll
    for (int off = 32; off; off >>= 1) { s += __shfl_xor(s, off); s2 += __shfl_xor(s2, off); }
    __shared__ float red[8];
    int wid = threadIdx.x >> 6;
    if ((threadIdx.x & 63) == 0) { red[wid] = s; red[4 + wid] = s2; }
    __syncthreads();
    s  = red[0] + red[1] + red[2] + red[3];
    s2 = red[4] + red[5] + red[6] + red[7];
    float mu  = s * (1.f / DM);
    float var = s2 * (1.f / DM) - mu * mu;
    float rstd = rsqrtf(var + EPSV);
    const float* mb = mod + b * 3072;
    float* hr = h + (size_t)row * DM;
#pragma unroll
    for (int i = 0; i < 4; ++i) {
        int d = threadIdx.x + i * 256;
        hr[d] = (v[i] - mu) * rstd * (1.f + mb[1024 + d]) + mb[d];
    }
}

// ---------------- fp32 GEMM: C(M,N) = A(M,K; lda) @ W(K,N; ldb), 64x64 tile, 4x4/thread
__global__ __launch_bounds__(256) void gemm_kernel(
    const float* __restrict__ A, int lda,
    const float* __restrict__ Bw, int ldb,
    float* __restrict__ C, int ldc,
    int K, int accum)
{
    __shared__ float As[16][68];
    __shared__ float Bs[16][68];
    int tid = threadIdx.x;
    int bm = blockIdx.y * 64;
    int bn = blockIdx.x * 64;
    int tx = tid & 15, ty = tid >> 4;
    int arow = tid >> 2, acol = (tid & 3) << 2;
    int brow = tid >> 4, bcol = (tid & 15) << 2;
    const float* aptr = A + (size_t)(bm + arow) * lda + acol;
    const float* bptr = Bw + (size_t)brow * ldb + bn + bcol;
    float acc[4][4] = {};
    for (int k0 = 0; k0 < K; k0 += 16) {
        float4 av = *(const float4*)(aptr + k0);
        float4 bv = *(const float4*)(bptr + (size_t)k0 * ldb);
        __syncthreads();
        As[acol + 0][arow] = av.x;
        As[acol + 1][arow] = av.y;
        As[acol + 2][arow] = av.z;
        As[acol + 3][arow] = av.w;
        *(float4*)&Bs[brow][bcol] = bv;
        __syncthreads();
#pragma unroll
        for (int k = 0; k < 16; ++k) {
            float4 a4 = *(const float4*)&As[k][ty << 2];
            float4 b4 = *(const float4*)&Bs[k][tx << 2];
            float ar[4] = {a4.x, a4.y, a4.z, a4.w};
            float br[4] = {b4.x, b4.y, b4.z, b4.w};
#pragma unroll
            for (int i = 0; i < 4; ++i)
#pragma unroll
                for (int j = 0; j < 4; ++j)
                    acc[i][j] = fmaf(ar[i], br[j], acc[i][j]);
        }
    }
#pragma unroll
    for (int i = 0; i < 4; ++i) {
        float* cp = C + (size_t)(bm + (ty << 2) + i) * ldc + bn + (tx << 2);
        float4 val = {acc[i][0], acc[i][1], acc[i][2], acc[i][3]};
        if (accum) {
            float4 old = *(const float4*)cp;
            val.x += old.x; val.y += old.y; val.z += old.z; val.w += old.w;
        }
        *(float4*)cp = val;
    }
}

// ---------------- silu in place on xs half of xz
__global__ void silu_xs_kernel(float* __restrict__ xz) {
    int idx = blockIdx.x * 256 + threadIdx.x;
    int row = idx >> 9, c = (idx & 511) << 2;
    float4* p = (float4*)(xz + (size_t)row * 4096 + c);
    float4 v = *p;
    v.x *= sigmoidf_(v.x); v.y *= sigmoidf_(v.y);
    v.z *= sigmoidf_(v.z); v.w *= sigmoidf_(v.w);
    *p = v;
}

// ---------------- dt = softplus(proj[:, :2048] + dt_bias), in place
__global__ void dtprep_kernel(float* __restrict__ proj, const float* __restrict__ dtb) {
    int idx = blockIdx.x * 256 + threadIdx.x;
    int row = idx >> 9, c = (idx & 511) << 2;
    float4* p = (float4*)(proj + (size_t)row * 2176 + c);
    float4 bv = *(const float4*)(dtb + c);
    float4 v = *p;
    v.x = softplus_(v.x + bv.x); v.y = softplus_(v.y + bv.y);
    v.z = softplus_(v.z + bv.z); v.w = softplus_(v.w + bv.w);
    *p = v;
}

// ---------------- selective scan, R3 rewrite.
// One wave per (b,d); lane = state. Scalarized d/b (readfirstlane) -> all row
// addresses are SALU/SMEM; B/C loads are saddr+const-lane-offset (0 addr VALU).
// y-reduction over 64 states via per-wave-private LDS transpose every 32 t
// (1 conflict-free ds_write/t + stride-65 row reads + 1 shfl), replacing the
// 6-stage butterfly. ~6 VALU/t main loop: exp2, 2 mul, fma, mul.
#define SLOAD(ib, t0_)                                                   \
    _Pragma("unroll")                                                    \
    for (int i_ = 0; i_ < 8; ++i_) {                                     \
        int tl_ = (t0_) + i_;  tl_ = tl_ > (LSEQ-1) ? (LSEQ-1) : tl_;    \
        int tg_ = REV ? (LSEQ-1) - tl_ : tl_;                            \
        const float* pr_ = projb + (size_t)tg_ * 2176;                   \
        dtb[ib][i_] = pr_[d];                                            \
        Bb[ib][i_]  = pr_[2048 + lane];                                  \
        Cb[ib][i_]  = pr_[2112 + lane];                                  \
        xb[ib][i_]  = xzb[(size_t)tg_ * 4096 + d];                       \
    }

#define SCOMP(ib, r0_)                                                   \
    _Pragma("unroll")                                                    \
    for (int i_ = 0; i_ < 8; ++i_) {                                     \
        float e_ = __builtin_amdgcn_exp2f(dtb[ib][i_] * Ae);             \
        float w_ = (dtb[ib][i_] * Bb[ib][i_]) * xb[ib][i_];              \
        hst = fmaf(hst, e_, w_);                                         \
        Lw[((r0_) + i_) * 65] = hst * Cb[ib][i_];                        \
    }

template <int REV>
__global__ __launch_bounds__(256) void scan_kernel(
    const float* __restrict__ proj, const float* __restrict__ xz,
    const float* __restrict__ A_log, const float* __restrict__ Dsk,
    float* __restrict__ y)
{
    __shared__ float lds[4][32 * 65];        // per-wave private 8.3 KB regions
    int lane = threadIdx.x & 63;
    int wv4 = threadIdx.x >> 6;
    int wave = blockIdx.x * 4 + wv4;
    int b = __builtin_amdgcn_readfirstlane(wave >> 11);
    int d = __builtin_amdgcn_readfirstlane(wave & 2047);
    float A  = -__expf(A_log[d * 64 + lane]);
    float Ae = A * 1.44269504f;              // fold log2(e) into A for exp2
    float Dv = Dsk[d];
    const float* projb = proj + (size_t)b * LSEQ * 2176;
    const float* xzb   = xz   + (size_t)b * LSEQ * 4096;
    float* yb = y + (size_t)b * LSEQ * 2048 + d;
    float* Lw = &lds[wv4][0] + lane;         // write base: [t&31][lane]
    const float* Lr = &lds[wv4][0] + (lane & 31) * 65 + (lane >> 5) * 32;
    float hst = 0.f;

    float dtb[2][8], Bb[2][8], Cb[2][8], xb[2][8];
    SLOAD(0, 0);
    for (int t0 = 0; t0 < LSEQ; t0 += 32) {
        SLOAD(1, t0 + 8);  SCOMP(0, 0);
        SLOAD(0, t0 + 16); SCOMP(1, 8);
        SLOAD(1, t0 + 24); SCOMP(0, 16);
        SLOAD(0, t0 + 32); SCOMP(1, 24);     // prefetch next chunk's first sub
        // epilogue: reduce 64 states for the 32 timesteps of this chunk
        float ssum = 0.f;
#pragma unroll
        for (int s_ = 0; s_ < 32; ++s_) ssum += Lr[s_];
        ssum += __shfl_xor(ssum, 32);        // combine half-rows; both halves hold sum
        if (lane < 32) {
            int tg = REV ? (LSEQ - 1) - (t0 + lane) : (t0 + lane);
            float xv = xzb[(size_t)tg * 4096 + d];
            float zv = xzb[(size_t)tg * 4096 + 2048 + d];
            yb[(size_t)tg * 2048] = fmaf(xv, Dv, ssum) * (zv * sigmoidf_(zv));
        }
    }
}

// ---------------- out = x + gate * v
__global__ void gated_add_kernel(const float* __restrict__ x, const float* __restrict__ v,
                                 const float* __restrict__ mod, float* __restrict__ out) {
    int idx = blockIdx.x * 256 + threadIdx.x;
    int row = idx >> 8, b = row >> 11, c = (idx & 255) << 2;
    size_t o = (size_t)row * 1024 + c;
    float4 xv = *(const float4*)(x + o);
    float4 hv = *(const float4*)(v + o);
    float4 gv = *(const float4*)(mod + b * 3072 + 2048 + c);
    float4 r = {fmaf(gv.x, hv.x, xv.x), fmaf(gv.y, hv.y, xv.y),
                fmaf(gv.z, hv.z, xv.z), fmaf(gv.w, hv.w, xv.w)};
    *(float4*)(out + o) = r;
}

// ---------------- g = silu(a) * b
__global__ void silumul_kernel(const float* __restrict__ a, const float* __restrict__ bb,
                               float* __restrict__ g) {
    int idx = blockIdx.x * 256 + threadIdx.x;
    size_t o = (size_t)idx << 2;
    float4 av = *(const float4*)(a + o);
    float4 bv = *(const float4*)(bb + o);
    float4 r = {av.x * sigmoidf_(av.x) * bv.x, av.y * sigmoidf_(av.y) * bv.y,
                av.z * sigmoidf_(av.z) * bv.z, av.w * sigmoidf_(av.w) * bv.w};
    *(float4*)(g + o) = r;
}

extern "C" void kernel_launch(void* const* d_in, const int* in_sizes, int n_in,
                              void* d_out, int out_size, void* d_ws, size_t ws_size,
                              hipStream_t stream) {
    const float* x         = (const float*)d_in[0];
    const float* c         = (const float*)d_in[1];
    const float* adw_mamba = (const float*)d_in[2];
    const float* adb_mamba = (const float*)d_in[3];
    const float* adw_mlp   = (const float*)d_in[4];
    const float* adb_mlp   = (const float*)d_in[5];
    const float* mlp_w1    = (const float*)d_in[6];
    const float* mlp_w2    = (const float*)d_in[7];
    const float* mlp_w3    = (const float*)d_in[8];
    const float* in_w[2]    = {(const float*)d_in[9],  (const float*)d_in[15]};
    const float* xproj_w[2] = {(const float*)d_in[10], (const float*)d_in[16]};
    const float* dt_bias[2] = {(const float*)d_in[11], (const float*)d_in[17]};
    const float* A_log[2]   = {(const float*)d_in[12], (const float*)d_in[18]};
    const float* Dsk[2]     = {(const float*)d_in[13], (const float*)d_in[19]};
    const float* out_w[2]   = {(const float*)d_in[14], (const float*)d_in[20]};
    float* out = (float*)d_out;

    // workspace layout (floats)
    float* ws   = (float*)d_ws;
    float* mod  = ws;                             // 2 * B * 3072 = 12288
    float* h    = mod  + 12288;                   // NTOK*1024
    float* xz   = h    + (size_t)NTOK * 1024;     // NTOK*4096
    float* proj = xz   + (size_t)NTOK * 4096;     // NTOK*2176
    float* yb   = proj + (size_t)NTOK * 2176;     // NTOK*2048
    float* hsum = yb   + (size_t)NTOK * 2048;     // NTOK*1024

    dim3 blk(256);

    mod_kernel<<<96, blk, 0, stream>>>(c, adw_mamba, adb_mamba, mod);
    mod_kernel<<<96, blk, 0, stream>>>(c, adw_mlp,   adb_mlp,   mod + 6144);
    adaln_kernel<<<NTOK, blk, 0, stream>>>(x, mod, h);

    for (int dir = 0; dir < 2; ++dir) {
        gemm_kernel<<<dim3(64, 64), blk, 0, stream>>>(h, 1024, in_w[dir], 4096, xz, 4096, 1024, 0);
        silu_xs_kernel<<<8192, blk, 0, stream>>>(xz);
        gemm_kernel<<<dim3(34, 64), blk, 0, stream>>>(xz, 4096, xproj_w[dir], 2176, proj, 2176, 2048, 0);
        dtprep_kernel<<<8192, blk, 0, stream>>>(proj, dt_bias[dir]);
        if (dir == 0)
            scan_kernel<0><<<1024, blk, 0, stream>>>(proj, xz, A_log[dir], Dsk[dir], yb);
        else
            scan_kernel<1><<<1024, blk, 0, stream>>>(proj, xz, A_log[dir], Dsk[dir], yb);
        gemm_kernel<<<dim3(16, 64), blk, 0, stream>>>(yb, 2048, out_w[dir], 1024, hsum, 1024, 2048, dir);
    }

    gated_add_kernel<<<4096, blk, 0, stream>>>(x, hsum, mod, out);
    adaln_kernel<<<NTOK, blk, 0, stream>>>(out, mod + 6144, h);
    gemm_kernel<<<dim3(32, 64), blk, 0, stream>>>(h, 1024, mlp_w1, 2048, xz, 2048, 1024, 0);
    gemm_kernel<<<dim3(32, 64), blk, 0, stream>>>(h, 1024, mlp_w2, 2048, xz + (size_t)NTOK * 2048, 2048, 1024, 0);
    silumul_kernel<<<8192, blk, 0, stream>>>(xz, xz + (size_t)NTOK * 2048, yb);
    gemm_kernel<<<dim3(16, 64), blk, 0, stream>>>(yb, 2048, mlp_w3, 1024, hsum, 1024, 2048, 0);
    gated_add_kernel<<<4096, blk, 0, stream>>>(out, hsum, mod + 6144, out);
}

// Round 4
// 3786.010 us; speedup vs baseline: 1.8514x; 1.2261x over previous
//
#include <hip/hip_runtime.h>
#include <math.h>

#define B_SZ 2
#define LSEQ 2048
#define DM   1024
#define DI   2048
#define DS   64
#define NTOK (B_SZ*LSEQ)
#define EPSV 1e-5f

static __device__ __forceinline__ float sigmoidf_(float v) {
    return 1.f / (1.f + __expf(-v));
}
static __device__ __forceinline__ float softplus_(float v) {
    return fmaxf(v, 0.f) + log1pf(__expf(-fabsf(v)));
}

// ---------------- adaln modulation
__global__ __launch_bounds__(256) void mod_kernel(const float* __restrict__ c,
                                                  const float* __restrict__ w,
                                                  const float* __restrict__ bias,
                                                  float* __restrict__ mod) {
    int jt = blockIdx.x * 32;
    int jj = threadIdx.x & 31, ks = threadIdx.x >> 5;
    int j = jt + jj;
    const float* c0 = c;
    const float* c1 = c + 1024;
    float a0 = 0.f, a1 = 0.f;
    int k0 = ks * 128;
#pragma unroll 4
    for (int k = k0; k < k0 + 128; ++k) {
        float wv = w[(size_t)k * 3072 + j];
        a0 = fmaf(c0[k], wv, a0);
        a1 = fmaf(c1[k], wv, a1);
    }
    __shared__ float red[2][8][32];
    red[0][ks][jj] = a0;
    red[1][ks][jj] = a1;
    __syncthreads();
    if (threadIdx.x < 64) {
        int bb = threadIdx.x >> 5, j2 = threadIdx.x & 31;
        float s = bias[jt + j2];
#pragma unroll
        for (int kk = 0; kk < 8; ++kk) s += red[bb][kk][j2];
        mod[bb * 3072 + jt + j2] = s;
    }
}

// ---------------- layernorm + adaln scale/shift
__global__ __launch_bounds__(256) void adaln_kernel(const float* __restrict__ x,
                                                    const float* __restrict__ mod,
                                                    float* __restrict__ h) {
    int row = blockIdx.x;
    int b = row >> 11;
    const float* xr = x + (size_t)row * DM;
    float v[4], s = 0.f, s2 = 0.f;
#pragma unroll
    for (int i = 0; i < 4; ++i) {
        v[i] = xr[threadIdx.x + i * 256];
        s += v[i]; s2 += v[i] * v[i];
    }
#pragma unroll
    for (int off = 32; off; off >>= 1) { s += __shfl_xor(s, off); s2 += __shfl_xor(s2, off); }
    __shared__ float red[8];
    int wid = threadIdx.x >> 6;
    if ((threadIdx.x & 63) == 0) { red[wid] = s; red[4 + wid] = s2; }
    __syncthreads();
    s  = red[0] + red[1] + red[2] + red[3];
    s2 = red[4] + red[5] + red[6] + red[7];
    float mu  = s * (1.f / DM);
    float var = s2 * (1.f / DM) - mu * mu;
    float rstd = rsqrtf(var + EPSV);
    const float* mb = mod + b * 3072;
    float* hr = h + (size_t)row * DM;
#pragma unroll
    for (int i = 0; i < 4; ++i) {
        int d = threadIdx.x + i * 256;
        hr[d] = (v[i] - mu) * rstd * (1.f + mb[1024 + d]) + mb[d];
    }
}

// ---------------- fp32 GEMM: C(M,N) = A(M,K; lda) @ W(K,N; ldb)
__global__ __launch_bounds__(256) void gemm_kernel(
    const float* __restrict__ A, int lda,
    const float* __restrict__ Bw, int ldb,
    float* __restrict__ C, int ldc,
    int K, int accum)
{
    __shared__ float As[16][68];
    __shared__ float Bs[16][68];
    int tid = threadIdx.x;
    int bm = blockIdx.y * 64;
    int bn = blockIdx.x * 64;
    int tx = tid & 15, ty = tid >> 4;
    int arow = tid >> 2, acol = (tid & 3) << 2;
    int brow = tid >> 4, bcol = (tid & 15) << 2;
    const float* aptr = A + (size_t)(bm + arow) * lda + acol;
    const float* bptr = Bw + (size_t)brow * ldb + bn + bcol;
    float acc[4][4] = {};
    for (int k0 = 0; k0 < K; k0 += 16) {
        float4 av = *(const float4*)(aptr + k0);
        float4 bv = *(const float4*)(bptr + (size_t)k0 * ldb);
        __syncthreads();
        As[acol + 0][arow] = av.x;
        As[acol + 1][arow] = av.y;
        As[acol + 2][arow] = av.z;
        As[acol + 3][arow] = av.w;
        *(float4*)&Bs[brow][bcol] = bv;
        __syncthreads();
#pragma unroll
        for (int k = 0; k < 16; ++k) {
            float4 a4 = *(const float4*)&As[k][ty << 2];
            float4 b4 = *(const float4*)&Bs[k][tx << 2];
            float ar[4] = {a4.x, a4.y, a4.z, a4.w};
            float br[4] = {b4.x, b4.y, b4.z, b4.w};
#pragma unroll
            for (int i = 0; i < 4; ++i)
#pragma unroll
                for (int j = 0; j < 4; ++j)
                    acc[i][j] = fmaf(ar[i], br[j], acc[i][j]);
        }
    }
#pragma unroll
    for (int i = 0; i < 4; ++i) {
        float* cp = C + (size_t)(bm + (ty << 2) + i) * ldc + bn + (tx << 2);
        float4 val = {acc[i][0], acc[i][1], acc[i][2], acc[i][3]};
        if (accum) {
            float4 old = *(const float4*)cp;
            val.x += old.x; val.y += old.y; val.z += old.z; val.w += old.w;
        }
        *(float4*)cp = val;
    }
}

// ---------------- fp32 GEMM, A transposed: C(M,N) = AT(K,M; lda)^T @ W(K,N; ldb)
__global__ __launch_bounds__(256) void gemm_at_kernel(
    const float* __restrict__ AT, int lda,
    const float* __restrict__ Bw, int ldb,
    float* __restrict__ C, int ldc,
    int K, int accum)
{
    __shared__ float As[16][68];
    __shared__ float Bs[16][68];
    int tid = threadIdx.x;
    int bm = blockIdx.y * 64;
    int bn = blockIdx.x * 64;
    int tx = tid & 15, ty = tid >> 4;
    int krow = tid >> 4, mcol = (tid & 15) << 2;
    const float* aptr = AT + (size_t)krow * lda + bm + mcol;
    const float* bptr = Bw + (size_t)krow * ldb + bn + mcol;
    float acc[4][4] = {};
    for (int k0 = 0; k0 < K; k0 += 16) {
        float4 av = *(const float4*)(aptr + (size_t)k0 * lda);
        float4 bv = *(const float4*)(bptr + (size_t)k0 * ldb);
        __syncthreads();
        *(float4*)&As[krow][mcol] = av;
        *(float4*)&Bs[krow][mcol] = bv;
        __syncthreads();
#pragma unroll
        for (int k = 0; k < 16; ++k) {
            float4 a4 = *(const float4*)&As[k][ty << 2];
            float4 b4 = *(const float4*)&Bs[k][tx << 2];
            float ar[4] = {a4.x, a4.y, a4.z, a4.w};
            float br[4] = {b4.x, b4.y, b4.z, b4.w};
#pragma unroll
            for (int i = 0; i < 4; ++i)
#pragma unroll
                for (int j = 0; j < 4; ++j)
                    acc[i][j] = fmaf(ar[i], br[j], acc[i][j]);
        }
    }
#pragma unroll
    for (int i = 0; i < 4; ++i) {
        float* cp = C + (size_t)(bm + (ty << 2) + i) * ldc + bn + (tx << 2);
        float4 val = {acc[i][0], acc[i][1], acc[i][2], acc[i][3]};
        if (accum) {
            float4 old = *(const float4*)cp;
            val.x += old.x; val.y += old.y; val.z += old.z; val.w += old.w;
        }
        *(float4*)cp = val;
    }
}

// ---------------- silu in place on xs half of xz
__global__ void silu_xs_kernel(float* __restrict__ xz) {
    int idx = blockIdx.x * 256 + threadIdx.x;
    int row = idx >> 9, c = (idx & 511) << 2;
    float4* p = (float4*)(xz + (size_t)row * 4096 + c);
    float4 v = *p;
    v.x *= sigmoidf_(v.x); v.y *= sigmoidf_(v.y);
    v.z *= sigmoidf_(v.z); v.w *= sigmoidf_(v.w);
    *p = v;
}

// ---------------- in-place transpose of square 4096x4096 (tile-pair swap)
__global__ __launch_bounds__(256) void transpose_inplace_kernel(float* __restrict__ M) {
    int bj = blockIdx.x, bi = blockIdx.y;
    if (bi > bj) return;
    __shared__ float ta[32][33], tb[32][33];
    int tx = threadIdx.x & 31, ty = threadIdx.x >> 5;
    size_t oA = ((size_t)bi * 32) * 4096 + (size_t)bj * 32;
    size_t oB = ((size_t)bj * 32) * 4096 + (size_t)bi * 32;
#pragma unroll
    for (int i = 0; i < 32; i += 8)
        ta[ty + i][tx] = M[oA + (size_t)(ty + i) * 4096 + tx];
    if (bi != bj) {
#pragma unroll
        for (int i = 0; i < 32; i += 8)
            tb[ty + i][tx] = M[oB + (size_t)(ty + i) * 4096 + tx];
    }
    __syncthreads();
#pragma unroll
    for (int i = 0; i < 32; i += 8)
        M[oB + (size_t)(ty + i) * 4096 + tx] = ta[tx][ty + i];
    if (bi != bj) {
#pragma unroll
        for (int i = 0; i < 32; i += 8)
            M[oA + (size_t)(ty + i) * 4096 + tx] = tb[tx][ty + i];
    }
}

// ---------------- out-of-place transpose with optional softplus+bias (for dt)
template <int OP>
__global__ __launch_bounds__(256) void transpose_op_kernel(
    const float* __restrict__ in, int lda,
    float* __restrict__ outp, int ldo,
    const float* __restrict__ bias)
{
    __shared__ float tile[32][33];
    int c0 = blockIdx.x * 32;   // input col tile (output row)
    int r0 = blockIdx.y * 32;   // input row tile
    int tx = threadIdx.x & 31, ty = threadIdx.x >> 5;
#pragma unroll
    for (int i = 0; i < 32; i += 8) {
        float v = in[(size_t)(r0 + ty + i) * lda + c0 + tx];
        if (OP) v = softplus_(v + bias[c0 + tx]);
        tile[ty + i][tx] = v;
    }
    __syncthreads();
#pragma unroll
    for (int i = 0; i < 32; i += 8)
        outp[(size_t)(c0 + ty + i) * ldo + r0 + tx] = tile[tx][ty + i];
}

// ---------------- selective scan, R4: all d-major contiguous access.
// dtT/xsT rows: uniform contiguous s_loads; B/C t-major (state-contiguous,
// shared across d); epilogue x/z/y: 128B coalesced segments along t.
#define SLOAD(ib, s0_)                                                   \
    _Pragma("unroll")                                                    \
    for (int i_ = 0; i_ < 8; ++i_) {                                     \
        int sl_ = (s0_) + i_;  sl_ = sl_ > (LSEQ-1) ? (LSEQ-1) : sl_;    \
        int tm_ = REV ? (LSEQ-1) - sl_ : sl_;                            \
        dts[ib][i_]  = sdt[tm_];                                         \
        xss[ib][i_]  = sxs[tm_];                                         \
        Bbuf[ib][i_] = projB[(size_t)tm_ * 2176 + lane];                 \
        Cbuf[ib][i_] = projB[(size_t)tm_ * 2176 + 64 + lane];            \
    }

#define SCOMP(ib, r0_)                                                   \
    _Pragma("unroll")                                                    \
    for (int i_ = 0; i_ < 8; ++i_) {                                     \
        float e_ = __builtin_amdgcn_exp2f(dts[ib][i_] * Ae);             \
        float u_ = dts[ib][i_] * xss[ib][i_];                            \
        hst = fmaf(hst, e_, u_ * Bbuf[ib][i_]);                          \
        Lw[((r0_) + i_) * 65] = hst * Cbuf[ib][i_];                      \
    }

template <int REV>
__global__ __launch_bounds__(256) void scan_kernel(
    const float* __restrict__ proj,   // [NTOK][2176], B/C at cols 2048..2175
    const float* __restrict__ dtT,    // [2048][4096] softplus'd dt, d-major
    const float* __restrict__ xzT,    // [4096][4096] rows 0..2047 silu(xs), 2048.. z
    const float* __restrict__ A_log, const float* __restrict__ Dsk,
    float* __restrict__ yT)           // [2048][4096] d-major
{
    __shared__ float lds[4][32 * 65];
    int lane = threadIdx.x & 63;
    int wv4 = threadIdx.x >> 6;
    int wave = blockIdx.x * 4 + wv4;
    int b = __builtin_amdgcn_readfirstlane(wave >> 11);
    int d = __builtin_amdgcn_readfirstlane(wave & 2047);
    float A  = -__expf(A_log[d * 64 + lane]);
    float Ae = A * 1.44269504f;
    float Dv = Dsk[d];
    const float* projB = proj + (size_t)b * LSEQ * 2176 + 2048;
    const float* sdt = dtT + (size_t)d * 4096 + b * 2048;
    const float* sxs = xzT + (size_t)d * 4096 + b * 2048;
    const float* szz = xzT + (size_t)(2048 + d) * 4096 + b * 2048;
    float* yrow = yT + (size_t)d * 4096 + b * 2048;
    float* Lw = &lds[wv4][0] + lane;
    const float* Lr = &lds[wv4][0] + (lane & 31) * 65 + (lane >> 5) * 32;
    float hst = 0.f;

    float dts[2][8], xss[2][8], Bbuf[2][8], Cbuf[2][8];
    SLOAD(0, 0);
    for (int s0 = 0; s0 < LSEQ; s0 += 32) {
        SLOAD(1, s0 + 8);  SCOMP(0, 0);
        SLOAD(0, s0 + 16); SCOMP(1, 8);
        SLOAD(1, s0 + 24); SCOMP(0, 16);
        SLOAD(0, s0 + 32); SCOMP(1, 24);
        float ssum = 0.f;
#pragma unroll
        for (int k = 0; k < 32; ++k) ssum += Lr[k];
        ssum += __shfl_xor(ssum, 32);
        if (lane < 32) {
            int tm = REV ? (LSEQ - 1) - (s0 + lane) : (s0 + lane);
            float xv = sxs[tm];
            float zv = szz[tm];
            yrow[tm] = fmaf(xv, Dv, ssum) * (zv * sigmoidf_(zv));
        }
    }
}

// ---------------- out = x + gate * v
__global__ void gated_add_kernel(const float* __restrict__ x, const float* __restrict__ v,
                                 const float* __restrict__ mod, float* __restrict__ out) {
    int idx = blockIdx.x * 256 + threadIdx.x;
    int row = idx >> 8, b = row >> 11, c = (idx & 255) << 2;
    size_t o = (size_t)row * 1024 + c;
    float4 xv = *(const float4*)(x + o);
    float4 hv = *(const float4*)(v + o);
    float4 gv = *(const float4*)(mod + b * 3072 + 2048 + c);
    float4 r = {fmaf(gv.x, hv.x, xv.x), fmaf(gv.y, hv.y, xv.y),
                fmaf(gv.z, hv.z, xv.z), fmaf(gv.w, hv.w, xv.w)};
    *(float4*)(out + o) = r;
}

// ---------------- g = silu(a) * b
__global__ void silumul_kernel(const float* __restrict__ a, const float* __restrict__ bb,
                               float* __restrict__ g) {
    int idx = blockIdx.x * 256 + threadIdx.x;
    size_t o = (size_t)idx << 2;
    float4 av = *(const float4*)(a + o);
    float4 bv = *(const float4*)(bb + o);
    float4 r = {av.x * sigmoidf_(av.x) * bv.x, av.y * sigmoidf_(av.y) * bv.y,
                av.z * sigmoidf_(av.z) * bv.z, av.w * sigmoidf_(av.w) * bv.w};
    *(float4*)(g + o) = r;
}

extern "C" void kernel_launch(void* const* d_in, const int* in_sizes, int n_in,
                              void* d_out, int out_size, void* d_ws, size_t ws_size,
                              hipStream_t stream) {
    const float* x         = (const float*)d_in[0];
    const float* c         = (const float*)d_in[1];
    const float* adw_mamba = (const float*)d_in[2];
    const float* adb_mamba = (const float*)d_in[3];
    const float* adw_mlp   = (const float*)d_in[4];
    const float* adb_mlp   = (const float*)d_in[5];
    const float* mlp_w1    = (const float*)d_in[6];
    const float* mlp_w2    = (const float*)d_in[7];
    const float* mlp_w3    = (const float*)d_in[8];
    const float* in_w[2]    = {(const float*)d_in[9],  (const float*)d_in[15]};
    const float* xproj_w[2] = {(const float*)d_in[10], (const float*)d_in[16]};
    const float* dt_bias[2] = {(const float*)d_in[11], (const float*)d_in[17]};
    const float* A_log[2]   = {(const float*)d_in[12], (const float*)d_in[18]};
    const float* Dsk[2]     = {(const float*)d_in[13], (const float*)d_in[19]};
    const float* out_w[2]   = {(const float*)d_in[14], (const float*)d_in[20]};
    float* out = (float*)d_out;

    // workspace layout (floats), total ~50.9M floats = 204 MB
    float* ws   = (float*)d_ws;
    float* mod  = ws;                                  // 12288
    float* h    = mod  + 12288;                        // NTOK*1024
    float* xz   = h    + (size_t)NTOK * 1024;          // NTOK*4096 (t-major, then in-place -> d-major)
    float* proj = xz   + (size_t)NTOK * 4096;          // NTOK*2176
    float* dtT  = proj + (size_t)NTOK * 2176;          // 2048*4096
    float* yT   = dtT  + (size_t)2048 * 4096;          // 2048*4096  (mlp: g)
    float* hsum = yT   + (size_t)2048 * 4096;          // NTOK*1024  (mlp: mlp_out)

    dim3 blk(256);

    mod_kernel<<<96, blk, 0, stream>>>(c, adw_mamba, adb_mamba, mod);
    mod_kernel<<<96, blk, 0, stream>>>(c, adw_mlp,   adb_mlp,   mod + 6144);
    adaln_kernel<<<NTOK, blk, 0, stream>>>(x, mod, h);

    for (int dir = 0; dir < 2; ++dir) {
        gemm_kernel<<<dim3(64, 64), blk, 0, stream>>>(h, 1024, in_w[dir], 4096, xz, 4096, 1024, 0);
        silu_xs_kernel<<<8192, blk, 0, stream>>>(xz);
        gemm_kernel<<<dim3(34, 64), blk, 0, stream>>>(xz, 4096, xproj_w[dir], 2176, proj, 2176, 2048, 0);
        // xz (4096x4096, t-major) -> d-major, in place
        transpose_inplace_kernel<<<dim3(128, 128), blk, 0, stream>>>(xz);
        // dt = softplus(proj[:, :2048] + bias), transposed to d-major
        transpose_op_kernel<1><<<dim3(64, 128), blk, 0, stream>>>(proj, 2176, dtT, 4096, dt_bias[dir]);
        if (dir == 0)
            scan_kernel<0><<<1024, blk, 0, stream>>>(proj, dtT, xz, A_log[dir], Dsk[dir], yT);
        else
            scan_kernel<1><<<1024, blk, 0, stream>>>(proj, dtT, xz, A_log[dir], Dsk[dir], yT);
        // hsum (+)= yT^T @ out_w   (M=4096, N=1024, K=2048)
        gemm_at_kernel<<<dim3(16, 64), blk, 0, stream>>>(yT, 4096, out_w[dir], 1024, hsum, 1024, 2048, dir);
    }

    gated_add_kernel<<<4096, blk, 0, stream>>>(x, hsum, mod, out);
    adaln_kernel<<<NTOK, blk, 0, stream>>>(out, mod + 6144, h);
    gemm_kernel<<<dim3(32, 64), blk, 0, stream>>>(h, 1024, mlp_w1, 2048, xz, 2048, 1024, 0);
    gemm_kernel<<<dim3(32, 64), blk, 0, stream>>>(h, 1024, mlp_w2, 2048, xz + (size_t)NTOK * 2048, 2048, 1024, 0);
    silumul_kernel<<<8192, blk, 0, stream>>>(xz, xz + (size_t)NTOK * 2048, yT);
    gemm_kernel<<<dim3(16, 64), blk, 0, stream>>>(yT, 2048, mlp_w3, 1024, hsum, 1024, 2048, 0);
    gated_add_kernel<<<4096, blk, 0, stream>>>(out, hsum, mod + 6144, out);
}

// Round 5
// 1258.352 us; speedup vs baseline: 5.5703x; 3.0087x over previous
//
#include <hip/hip_runtime.h>
#include <hip/hip_bf16.h>
#include <math.h>

#define B_SZ 2
#define LSEQ 2048
#define DM   1024
#define DI   2048
#define NTOK (B_SZ*LSEQ)
#define EPSV 1e-5f

typedef __attribute__((ext_vector_type(8))) short short8v;
typedef __attribute__((ext_vector_type(4))) short short4v;
typedef __attribute__((ext_vector_type(4))) float f4v;

static __device__ __forceinline__ float sigmoidf_(float v) {
    return 1.f / (1.f + __expf(-v));
}
static __device__ __forceinline__ float softplus_(float v) {
    return fmaxf(v, 0.f) + log1pf(__expf(-fabsf(v)));
}
static __device__ __forceinline__ short f2bf(float f) {
    __hip_bfloat16 h = __float2bfloat16(f);   // RNE
    return *reinterpret_cast<short*>(&h);
}

// ---------------- adaln modulation: mod[b][j] = bias[j] + sum_k c[b][k]*w[k][j]
__global__ __launch_bounds__(256) void mod_kernel(const float* __restrict__ c,
                                                  const float* __restrict__ w,
                                                  const float* __restrict__ bias,
                                                  float* __restrict__ mod) {
    int jt = blockIdx.x * 32;
    int jj = threadIdx.x & 31, ks = threadIdx.x >> 5;
    int j = jt + jj;
    const float* c0 = c;
    const float* c1 = c + 1024;
    float a0 = 0.f, a1 = 0.f;
    int k0 = ks * 128;
#pragma unroll 4
    for (int k = k0; k < k0 + 128; ++k) {
        float wv = w[(size_t)k * 3072 + j];
        a0 = fmaf(c0[k], wv, a0);
        a1 = fmaf(c1[k], wv, a1);
    }
    __shared__ float red[2][8][32];
    red[0][ks][jj] = a0;
    red[1][ks][jj] = a1;
    __syncthreads();
    if (threadIdx.x < 64) {
        int bb = threadIdx.x >> 5, j2 = threadIdx.x & 31;
        float s = bias[jt + j2];
#pragma unroll
        for (int kk = 0; kk < 8; ++kk) s += red[bb][kk][j2];
        mod[bb * 3072 + jt + j2] = s;
    }
}

// ---------------- layernorm + adaln scale/shift -> bf16 (feeds GEMMs only)
__global__ __launch_bounds__(256) void adaln_kernel(const float* __restrict__ x,
                                                    const float* __restrict__ mod,
                                                    __hip_bfloat16* __restrict__ h) {
    int row = blockIdx.x;
    int b = row >> 11;
    const float* xr = x + (size_t)row * DM;
    float v[4], s = 0.f, s2 = 0.f;
#pragma unroll
    for (int i = 0; i < 4; ++i) {
        v[i] = xr[threadIdx.x + i * 256];
        s += v[i]; s2 += v[i] * v[i];
    }
#pragma unroll
    for (int off = 32; off; off >>= 1) { s += __shfl_xor(s, off); s2 += __shfl_xor(s2, off); }
    __shared__ float red[8];
    int wid = threadIdx.x >> 6;
    if ((threadIdx.x & 63) == 0) { red[wid] = s; red[4 + wid] = s2; }
    __syncthreads();
    s  = red[0] + red[1] + red[2] + red[3];
    s2 = red[4] + red[5] + red[6] + red[7];
    float mu  = s * (1.f / DM);
    float var = s2 * (1.f / DM) - mu * mu;
    float rstd = rsqrtf(var + EPSV);
    const float* mb = mod + b * 3072;
    __hip_bfloat16* hr = h + (size_t)row * DM;
#pragma unroll
    for (int i = 0; i < 4; ++i) {
        int d = threadIdx.x + i * 256;
        hr[d] = __float2bfloat16((v[i] - mu) * rstd * (1.f + mb[1024 + d]) + mb[d]);
    }
}

// ---------------- bf16 MFMA GEMM: C(M,N) fp32 = A(M,K) @ Bt(N,K)^T
// 128x128 tile, BK=32, 4 waves of 64x64 (4x4 frags of 16x16x32 MFMA).
// LDS rows padded to 40 shorts (80B) to spread ds_read_b128 bank starts.
template <int ACCUM>
__global__ __launch_bounds__(256) void gemm_bf16_kernel(
    const short* __restrict__ A, int lda,
    const short* __restrict__ Bt, int ldb,
    float* __restrict__ C, int ldc, int K)
{
    __shared__ short As[128][40];
    __shared__ short Bs[128][40];
    int tid = threadIdx.x;
    int m0 = blockIdx.y * 128, n0 = blockIdx.x * 128;
    int wave = tid >> 6, lane = tid & 63;
    int wm = (wave & 1) * 64, wn = (wave >> 1) * 64;
    int srow = tid >> 2, sq = (tid & 3) * 8;          // stage: row, 8-short chunk
    const short* aptr = A + (size_t)(m0 + srow) * lda + sq;
    const short* bptr = Bt + (size_t)(n0 + srow) * ldb + sq;
    int fr = lane & 15, fq = lane >> 4;               // frag row-in-16, quad
    f4v acc[4][4];
#pragma unroll
    for (int i = 0; i < 4; ++i)
#pragma unroll
        for (int j = 0; j < 4; ++j) acc[i][j] = (f4v){0.f, 0.f, 0.f, 0.f};

    short8v a0 = *(const short8v*)(aptr);
    short8v a1 = *(const short8v*)(aptr + 64 * (size_t)lda);
    short8v b0 = *(const short8v*)(bptr);
    short8v b1 = *(const short8v*)(bptr + 64 * (size_t)ldb);
    for (int k0 = 0; k0 < K; k0 += 32) {
        __syncthreads();
        *(short8v*)&As[srow][sq]      = a0;
        *(short8v*)&As[srow + 64][sq] = a1;
        *(short8v*)&Bs[srow][sq]      = b0;
        *(short8v*)&Bs[srow + 64][sq] = b1;
        __syncthreads();
        if (k0 + 32 < K) {                            // prefetch next K-block
            a0 = *(const short8v*)(aptr + k0 + 32);
            a1 = *(const short8v*)(aptr + 64 * (size_t)lda + k0 + 32);
            b0 = *(const short8v*)(bptr + k0 + 32);
            b1 = *(const short8v*)(bptr + 64 * (size_t)ldb + k0 + 32);
        }
        short8v af[4], bf[4];
#pragma unroll
        for (int i = 0; i < 4; ++i) af[i] = *(const short8v*)&As[wm + i * 16 + fr][fq * 8];
#pragma unroll
        for (int j = 0; j < 4; ++j) bf[j] = *(const short8v*)&Bs[wn + j * 16 + fr][fq * 8];
#pragma unroll
        for (int i = 0; i < 4; ++i)
#pragma unroll
            for (int j = 0; j < 4; ++j)
                acc[i][j] = __builtin_amdgcn_mfma_f32_16x16x32_bf16(af[i], bf[j], acc[i][j], 0, 0, 0);
    }
    // C/D layout: col = lane&15, row = (lane>>4)*4 + reg
#pragma unroll
    for (int i = 0; i < 4; ++i)
#pragma unroll
        for (int j = 0; j < 4; ++j) {
#pragma unroll
            for (int r = 0; r < 4; ++r) {
                int row = m0 + wm + i * 16 + fq * 4 + r;
                int col = n0 + wn + j * 16 + fr;
                float* cp = C + (size_t)row * ldc + col;
                if (ACCUM) *cp += acc[i][j][r]; else *cp = acc[i][j][r];
            }
        }
}

// ---------------- weight cast+transpose: w[K][N] fp32 -> wT[N][K] bf16
__global__ __launch_bounds__(256) void wcast_kernel(const float* __restrict__ w,
                                                    int K, int N,
                                                    short* __restrict__ wT) {
    __shared__ short tile[32][33];
    int c0 = blockIdx.x * 32, r0 = blockIdx.y * 32;   // c over N, r over K
    int tx = threadIdx.x & 31, ty = threadIdx.x >> 5;
#pragma unroll
    for (int i = 0; i < 32; i += 8)
        tile[ty + i][tx] = f2bf(w[(size_t)(r0 + ty + i) * N + c0 + tx]);
    __syncthreads();
#pragma unroll
    for (int i = 0; i < 32; i += 8)
        wT[(size_t)(c0 + ty + i) * K + r0 + tx] = tile[tx][ty + i];
}

// ---------------- silu on xs half of xz (fp32 in place, for scan) + bf16 copy (for GEMM)
__global__ void silu_xs_kernel(float* __restrict__ xz, __hip_bfloat16* __restrict__ xsb) {
    int idx = blockIdx.x * 256 + threadIdx.x;
    int row = idx >> 9, c = (idx & 511) << 2;
    float4* p = (float4*)(xz + (size_t)row * 4096 + c);
    float4 v = *p;
    v.x *= sigmoidf_(v.x); v.y *= sigmoidf_(v.y);
    v.z *= sigmoidf_(v.z); v.w *= sigmoidf_(v.w);
    *p = v;
    short4v s = {f2bf(v.x), f2bf(v.y), f2bf(v.z), f2bf(v.w)};
    *(short4v*)((short*)xsb + (size_t)row * 2048 + c) = s;
}

// ---------------- in-place transpose of square 4096x4096 fp32 (tile-pair swap)
__global__ __launch_bounds__(256) void transpose_inplace_kernel(float* __restrict__ M) {
    int bj = blockIdx.x, bi = blockIdx.y;
    if (bi > bj) return;
    __shared__ float ta[32][33], tb[32][33];
    int tx = threadIdx.x & 31, ty = threadIdx.x >> 5;
    size_t oA = ((size_t)bi * 32) * 4096 + (size_t)bj * 32;
    size_t oB = ((size_t)bj * 32) * 4096 + (size_t)bi * 32;
#pragma unroll
    for (int i = 0; i < 32; i += 8)
        ta[ty + i][tx] = M[oA + (size_t)(ty + i) * 4096 + tx];
    if (bi != bj) {
#pragma unroll
        for (int i = 0; i < 32; i += 8)
            tb[ty + i][tx] = M[oB + (size_t)(ty + i) * 4096 + tx];
    }
    __syncthreads();
#pragma unroll
    for (int i = 0; i < 32; i += 8)
        M[oB + (size_t)(ty + i) * 4096 + tx] = ta[tx][ty + i];
    if (bi != bj) {
#pragma unroll
        for (int i = 0; i < 32; i += 8)
            M[oA + (size_t)(ty + i) * 4096 + tx] = tb[tx][ty + i];
    }
}

// ---------------- dt: softplus(proj[:, :2048]+bias), transposed -> bf16 [2048][4096]
__global__ __launch_bounds__(256) void transpose_dt_kernel(const float* __restrict__ proj,
                                                           const float* __restrict__ bias,
                                                           short* __restrict__ dtT) {
    __shared__ short tile[32][33];
    int c0 = blockIdx.x * 32, r0 = blockIdx.y * 32;   // c over d (2048), r over tok (4096)
    int tx = threadIdx.x & 31, ty = threadIdx.x >> 5;
#pragma unroll
    for (int i = 0; i < 32; i += 8) {
        float v = proj[(size_t)(r0 + ty + i) * 2176 + c0 + tx];
        tile[ty + i][tx] = f2bf(softplus_(v + bias[c0 + tx]));
    }
    __syncthreads();
#pragma unroll
    for (int i = 0; i < 32; i += 8)
        dtT[(size_t)(c0 + ty + i) * 4096 + r0 + tx] = tile[tx][ty + i];
}

// ---------------- bf16 transpose: in[2048][4096] -> out[4096][2048]
__global__ __launch_bounds__(256) void transpose_bf16_kernel(const short* __restrict__ in,
                                                             short* __restrict__ outp) {
    __shared__ short tile[32][33];
    int c0 = blockIdx.x * 32, r0 = blockIdx.y * 32;   // c over 4096, r over 2048
    int tx = threadIdx.x & 31, ty = threadIdx.x >> 5;
#pragma unroll
    for (int i = 0; i < 32; i += 8)
        tile[ty + i][tx] = in[(size_t)(r0 + ty + i) * 4096 + c0 + tx];
    __syncthreads();
#pragma unroll
    for (int i = 0; i < 32; i += 8)
        outp[(size_t)(c0 + ty + i) * 2048 + r0 + tx] = tile[tx][ty + i];
}

// ---------------- selective scan (R4 structure; dt bf16 in, y bf16 out)
#define SLOAD(ib, s0_)                                                   \
    _Pragma("unroll")                                                    \
    for (int i_ = 0; i_ < 8; ++i_) {                                     \
        int sl_ = (s0_) + i_;  sl_ = sl_ > (LSEQ-1) ? (LSEQ-1) : sl_;    \
        int tm_ = REV ? (LSEQ-1) - sl_ : sl_;                            \
        dts[ib][i_]  = __bfloat162float(sdt[tm_]);                       \
        xss[ib][i_]  = sxs[tm_];                                         \
        Bbuf[ib][i_] = projB[(size_t)tm_ * 2176 + lane];                 \
        Cbuf[ib][i_] = projB[(size_t)tm_ * 2176 + 64 + lane];            \
    }

#define SCOMP(ib, r0_)                                                   \
    _Pragma("unroll")                                                    \
    for (int i_ = 0; i_ < 8; ++i_) {                                     \
        float e_ = __builtin_amdgcn_exp2f(dts[ib][i_] * Ae);             \
        float u_ = dts[ib][i_] * xss[ib][i_];                            \
        hst = fmaf(hst, e_, u_ * Bbuf[ib][i_]);                          \
        Lw[((r0_) + i_) * 65] = hst * Cbuf[ib][i_];                      \
    }

template <int REV>
__global__ __launch_bounds__(256) void scan_kernel(
    const float* __restrict__ proj,          // [NTOK][2176], B/C at cols 2048..
    const __hip_bfloat16* __restrict__ dtT,  // [2048][4096] bf16, d-major
    const float* __restrict__ xzT,           // [4096][4096] fp32 d-major
    const float* __restrict__ A_log, const float* __restrict__ Dsk,
    __hip_bfloat16* __restrict__ yT)         // [2048][4096] bf16 d-major
{
    __shared__ float lds[4][32 * 65];
    int lane = threadIdx.x & 63;
    int wv4 = threadIdx.x >> 6;
    int wave = blockIdx.x * 4 + wv4;
    int b = __builtin_amdgcn_readfirstlane(wave >> 11);
    int d = __builtin_amdgcn_readfirstlane(wave & 2047);
    float A  = -__expf(A_log[d * 64 + lane]);
    float Ae = A * 1.44269504f;
    float Dv = Dsk[d];
    const float* projB = proj + (size_t)b * LSEQ * 2176 + 2048;
    const __hip_bfloat16* sdt = dtT + (size_t)d * 4096 + b * 2048;
    const float* sxs = xzT + (size_t)d * 4096 + b * 2048;
    const float* szz = xzT + (size_t)(2048 + d) * 4096 + b * 2048;
    __hip_bfloat16* yrow = yT + (size_t)d * 4096 + b * 2048;
    float* Lw = &lds[wv4][0] + lane;
    const float* Lr = &lds[wv4][0] + (lane & 31) * 65 + (lane >> 5) * 32;
    float hst = 0.f;

    float dts[2][8], xss[2][8], Bbuf[2][8], Cbuf[2][8];
    SLOAD(0, 0);
    for (int s0 = 0; s0 < LSEQ; s0 += 32) {
        SLOAD(1, s0 + 8);  SCOMP(0, 0);
        SLOAD(0, s0 + 16); SCOMP(1, 8);
        SLOAD(1, s0 + 24); SCOMP(0, 16);
        SLOAD(0, s0 + 32); SCOMP(1, 24);
        float ssum = 0.f;
#pragma unroll
        for (int k = 0; k < 32; ++k) ssum += Lr[k];
        ssum += __shfl_xor(ssum, 32);
        if (lane < 32) {
            int tm = REV ? (LSEQ - 1) - (s0 + lane) : (s0 + lane);
            float xv = sxs[tm];
            float zv = szz[tm];
            yrow[tm] = __float2bfloat16(fmaf(xv, Dv, ssum) * (zv * sigmoidf_(zv)));
        }
    }
}

// ---------------- out = x + gate * v
__global__ void gated_add_kernel(const float* __restrict__ x, const float* __restrict__ v,
                                 const float* __restrict__ mod, float* __restrict__ out) {
    int idx = blockIdx.x * 256 + threadIdx.x;
    int row = idx >> 8, b = row >> 11, c = (idx & 255) << 2;
    size_t o = (size_t)row * 1024 + c;
    float4 xv = *(const float4*)(x + o);
    float4 hv = *(const float4*)(v + o);
    float4 gv = *(const float4*)(mod + b * 3072 + 2048 + c);
    float4 r = {fmaf(gv.x, hv.x, xv.x), fmaf(gv.y, hv.y, xv.y),
                fmaf(gv.z, hv.z, xv.z), fmaf(gv.w, hv.w, xv.w)};
    *(float4*)(out + o) = r;
}

// ---------------- g = silu(a) * b  -> bf16
__global__ void silumul_kernel(const float* __restrict__ a, const float* __restrict__ bb,
                               __hip_bfloat16* __restrict__ g) {
    int idx = blockIdx.x * 256 + threadIdx.x;
    size_t o = (size_t)idx << 2;
    float4 av = *(const float4*)(a + o);
    float4 bv = *(const float4*)(bb + o);
    short4v r = {f2bf(av.x * sigmoidf_(av.x) * bv.x), f2bf(av.y * sigmoidf_(av.y) * bv.y),
                 f2bf(av.z * sigmoidf_(av.z) * bv.z), f2bf(av.w * sigmoidf_(av.w) * bv.w)};
    *(short4v*)((short*)g + o) = r;
}

extern "C" void kernel_launch(void* const* d_in, const int* in_sizes, int n_in,
                              void* d_out, int out_size, void* d_ws, size_t ws_size,
                              hipStream_t stream) {
    const float* x         = (const float*)d_in[0];
    const float* c         = (const float*)d_in[1];
    const float* adw_mamba = (const float*)d_in[2];
    const float* adb_mamba = (const float*)d_in[3];
    const float* adw_mlp   = (const float*)d_in[4];
    const float* adb_mlp   = (const float*)d_in[5];
    const float* mlp_w1    = (const float*)d_in[6];
    const float* mlp_w2    = (const float*)d_in[7];
    const float* mlp_w3    = (const float*)d_in[8];
    const float* in_w[2]    = {(const float*)d_in[9],  (const float*)d_in[15]};
    const float* xproj_w[2] = {(const float*)d_in[10], (const float*)d_in[16]};
    const float* dt_bias[2] = {(const float*)d_in[11], (const float*)d_in[17]};
    const float* A_log[2]   = {(const float*)d_in[12], (const float*)d_in[18]};
    const float* Dsk[2]     = {(const float*)d_in[13], (const float*)d_in[19]};
    const float* out_w[2]   = {(const float*)d_in[14], (const float*)d_in[20]};
    float* out = (float*)d_out;

    // workspace (float units), total ~54.3M floats = 217 MB
    float* ws    = (float*)d_ws;
    float* mod   = ws;                                  // 12288
    short* h_bf  = (short*)(ws + 12288);                // 4096x1024 bf16 (h / h2)
    float* xz    = ws + 12288 + 2097152;                // 4096x4096 fp32
    float* proj  = xz + 16777216;                       // 4096x2176 fp32
    float* scr   = proj + 8912896;                      // 4.19M floats: xs_bf | dtT | yb (time-shared)
    short* xs_bf = (short*)scr;                         // 4096x2048 bf16
    short* dtT   = (short*)scr;                         // 2048x4096 bf16 (after proj GEMM done)
    short* ybtok = (short*)scr;                         // 4096x2048 bf16 (after scan done)
    short* yTb   = (short*)(scr + 4194304);             // 2048x4096 bf16 (scan out; later g)
    float* hsum  = scr + 8388608;                       // 4096x1024 fp32
    short* wb    = (short*)(hsum + 4194304);            // 27.8M shorts of bf16 weights
    short* inw_b[2]  = {wb,            wb + 4194304};
    short* xpj_b[2]  = {wb + 8388608,  wb + 12845056};
    short* outw_b[2] = {wb + 17301504, wb + 19398656};
    short* w1_b = wb + 21495808;
    short* w2_b = wb + 23592960;
    short* w3_b = wb + 25690112;

    dim3 blk(256);

    // weight casts+transposes ([K][N] fp32 -> [N][K] bf16)
    for (int dir = 0; dir < 2; ++dir) {
        wcast_kernel<<<dim3(128, 32), blk, 0, stream>>>(in_w[dir],   1024, 4096, inw_b[dir]);
        wcast_kernel<<<dim3(68, 64),  blk, 0, stream>>>(xproj_w[dir],2048, 2176, xpj_b[dir]);
        wcast_kernel<<<dim3(32, 64),  blk, 0, stream>>>(out_w[dir],  2048, 1024, outw_b[dir]);
    }
    wcast_kernel<<<dim3(64, 32), blk, 0, stream>>>(mlp_w1, 1024, 2048, w1_b);
    wcast_kernel<<<dim3(64, 32), blk, 0, stream>>>(mlp_w2, 1024, 2048, w2_b);
    wcast_kernel<<<dim3(32, 64), blk, 0, stream>>>(mlp_w3, 2048, 1024, w3_b);

    mod_kernel<<<96, blk, 0, stream>>>(c, adw_mamba, adb_mamba, mod);
    mod_kernel<<<96, blk, 0, stream>>>(c, adw_mlp,   adb_mlp,   mod + 6144);
    adaln_kernel<<<NTOK, blk, 0, stream>>>(x, mod, (__hip_bfloat16*)h_bf);

    for (int dir = 0; dir < 2; ++dir) {
        // xz = h @ in_w   (M=4096,N=4096,K=1024)
        gemm_bf16_kernel<0><<<dim3(32, 32), blk, 0, stream>>>(h_bf, 1024, inw_b[dir], 1024, xz, 4096, 1024);
        silu_xs_kernel<<<8192, blk, 0, stream>>>(xz, (__hip_bfloat16*)xs_bf);
        // proj = xs @ xproj_w  (M=4096,N=2176,K=2048)
        gemm_bf16_kernel<0><<<dim3(17, 32), blk, 0, stream>>>(xs_bf, 2048, xpj_b[dir], 2048, proj, 2176, 2048);
        transpose_inplace_kernel<<<dim3(128, 128), blk, 0, stream>>>(xz);
        transpose_dt_kernel<<<dim3(64, 128), blk, 0, stream>>>(proj, dt_bias[dir], dtT);
        if (dir == 0)
            scan_kernel<0><<<1024, blk, 0, stream>>>(proj, (const __hip_bfloat16*)dtT, xz,
                                                     A_log[dir], Dsk[dir], (__hip_bfloat16*)yTb);
        else
            scan_kernel<1><<<1024, blk, 0, stream>>>(proj, (const __hip_bfloat16*)dtT, xz,
                                                     A_log[dir], Dsk[dir], (__hip_bfloat16*)yTb);
        // yTb [2048][4096] -> token-major [4096][2048] (overwrites dtT region; dtT dead)
        transpose_bf16_kernel<<<dim3(128, 64), blk, 0, stream>>>(yTb, ybtok);
        // hsum (+)= y @ out_w  (M=4096,N=1024,K=2048)
        if (dir == 0)
            gemm_bf16_kernel<0><<<dim3(8, 32), blk, 0, stream>>>(ybtok, 2048, outw_b[dir], 2048, hsum, 1024, 2048);
        else
            gemm_bf16_kernel<1><<<dim3(8, 32), blk, 0, stream>>>(ybtok, 2048, outw_b[dir], 2048, hsum, 1024, 2048);
    }

    gated_add_kernel<<<4096, blk, 0, stream>>>(x, hsum, mod, out);
    adaln_kernel<<<NTOK, blk, 0, stream>>>(out, mod + 6144, (__hip_bfloat16*)h_bf);
    // mlp: a = h2@w1, b = h2@w2 (fp32 into xz halves), g = silu(a)*b (bf16 in yTb region)
    gemm_bf16_kernel<0><<<dim3(16, 32), blk, 0, stream>>>(h_bf, 1024, w1_b, 1024, xz, 2048, 1024);
    gemm_bf16_kernel<0><<<dim3(16, 32), blk, 0, stream>>>(h_bf, 1024, w2_b, 1024, xz + (size_t)NTOK * 2048, 2048, 1024);
    silumul_kernel<<<8192, blk, 0, stream>>>(xz, xz + (size_t)NTOK * 2048, (__hip_bfloat16*)yTb);
    // mlp_out = g @ w3  (M=4096,N=1024,K=2048)
    gemm_bf16_kernel<0><<<dim3(8, 32), blk, 0, stream>>>(yTb, 2048, w3_b, 2048, hsum, 1024, 2048);
    gated_add_kernel<<<4096, blk, 0, stream>>>(out, hsum, mod + 6144, out);
}